// Round 3
// baseline (993.178 us; speedup 1.0000x reference)
//
#include <hip/hip_runtime.h>
#include <hip/hip_bf16.h>

#define VOCAB 32000
#define EMB   64
#define HID   64
#define NB    16
#define NS    256
#define G3    192   // 3*HID

typedef __bf16 bf16x8  __attribute__((ext_vector_type(8)));
typedef short  short8  __attribute__((ext_vector_type(8)));
typedef short  short4v __attribute__((ext_vector_type(4)));
typedef float  floatx4 __attribute__((ext_vector_type(4)));

__device__ __forceinline__ float bf2f(__hip_bfloat16 v) { return __bfloat162float(v); }

// RNE fp32 -> bf16 bit pattern (no NaN inputs possible here)
__device__ __forceinline__ short f2bf_bits(float f) {
    unsigned int u = __float_as_uint(f);
    unsigned int r = (u + 0x7FFFu + ((u >> 16) & 1u)) >> 16;
    return (short)r;
}

// bf16 bit pattern -> float
__device__ __forceinline__ float bfbits2f(short b) {
    return __uint_as_float(((unsigned int)(unsigned short)b) << 16);
}

// Runtime dtype detection: true if the array at p holds bf16 data, false if fp32.
__device__ __forceinline__ bool detect_bf16(const void* p) {
    const unsigned int* w = (const unsigned int*)p;
    unsigned int word = w[threadIdx.x & 63];
    unsigned int e = (word >> 7) & 0xFFu;
    int pred = (e >= 115u) && (e <= 130u);
    unsigned long long m = __ballot(pred);
    return __popcll(m) > 32;
}

// ---------------------------------------------------------------------------
// K1: xpt[s][gate][b][u] = sum_e emb[tok[b][s]][e] * w_ih[gate*64+u][e] + b_ih
// Transposed layout so K2's MFMA lanes read their gate inputs as one float4.
// One block per s; thread g = gate*64 + u owns one w_ih row in registers and
// loops the 16 batches over LDS-staged embedding vectors (broadcast reads).
// ---------------------------------------------------------------------------
__global__ __launch_bounds__(G3) void k_embed_proj_t(
    const int* __restrict__ tokens,
    const void* __restrict__ emb_raw,
    const void* __restrict__ w_ih_raw,
    const void* __restrict__ b_ih_raw,
    float* __restrict__ xpt)
{
    const bool isbf = detect_bf16(w_ih_raw);
    const int s   = blockIdx.x;
    const int tid = threadIdx.x;

    __shared__ int   tok_s[NB];
    __shared__ float e_s[NB][EMB];

    if (tid < NB) tok_s[tid] = tokens[tid * NS + s];
    __syncthreads();
    for (int idx = tid; idx < NB * EMB; idx += G3) {
        const int b = idx >> 6, e = idx & 63;
        const int t = tok_s[b];
        e_s[b][e] = isbf ? bf2f(((const __hip_bfloat16*)emb_raw)[t * EMB + e])
                         : ((const float*)emb_raw)[t * EMB + e];
    }
    __syncthreads();

    float wf[EMB];
    if (isbf) {
        const __hip_bfloat16* wrow = (const __hip_bfloat16*)w_ih_raw + tid * EMB;
#pragma unroll
        for (int k0 = 0; k0 < EMB; k0 += 8) {
            bf16x8 wv = *reinterpret_cast<const bf16x8*>(wrow + k0);
#pragma unroll
            for (int j = 0; j < 8; ++j) wf[k0 + j] = (float)wv[j];
        }
    } else {
        const float* wrow = (const float*)w_ih_raw + tid * EMB;
#pragma unroll
        for (int k0 = 0; k0 < EMB; k0 += 4) {
            floatx4 wv = *reinterpret_cast<const floatx4*>(wrow + k0);
#pragma unroll
            for (int j = 0; j < 4; ++j) wf[k0 + j] = wv[j];
        }
    }
    const float bias = isbf ? bf2f(((const __hip_bfloat16*)b_ih_raw)[tid])
                            : ((const float*)b_ih_raw)[tid];

    const int gam = tid >> 6;       // gate 0..2 (r,z,n)
    const int u   = tid & 63;       // unit
    float* orow = xpt + ((size_t)(s * 3 + gam) * NB) * HID + u;
    for (int b = 0; b < NB; ++b) {
        float acc = bias;
#pragma unroll
        for (int k0 = 0; k0 < EMB; k0 += 4) {
            floatx4 e4 = *reinterpret_cast<const floatx4*>(&e_s[b][k0]);
            acc += e4[0] * wf[k0] + e4[1] * wf[k0 + 1]
                 + e4[2] * wf[k0 + 2] + e4[3] * wf[k0 + 3];
        }
        orow[b * HID] = acc;   // lanes u=0..63 contiguous -> 256B coalesced
    }
}

// ---------------------------------------------------------------------------
// K2: GRU scan via MFMA. ONE block, 4 waves; per step:
//   hp(192x16) = W_hh(192x64) . H(64x16)   [M = 4 waves x 3 gates x 16 rows,
//                                           N = 16 batches, K = 64 = 2 halves]
// Wave w owns units [16w,16w+16); each lane owns 4 units x 1 batch (matches
// the MFMA C layout col=lane&15,row=quad*4+i). W_hh A-frags staged once in
// registers. Precision: split-bf16 (h = hi+lo, W = hi+lo when fp32 input) so
// the recurrence stays ~fp32-accurate. One barrier/step (lgkmcnt-only, HK
// pattern); LDS h planes double-buffered.
// ---------------------------------------------------------------------------
__global__ __launch_bounds__(256, 1) void k_gru_scan(
    const float* __restrict__ xpt,
    const void* __restrict__ w_hh_raw,
    const void* __restrict__ b_hh_raw,
    __hip_bfloat16* __restrict__ hs)
{
    const bool isbf = detect_bf16(w_hh_raw);
    const int tid  = threadIdx.x;
    const int w    = tid >> 6;       // wave 0..3 -> unit slab 16w
    const int lane = tid & 63;
    const int quad = lane >> 4;
    const int l15  = lane & 15;      // batch

    // h double-buffer: [buf][hi/lo][batch][unit padded to 72]
    __shared__ __align__(16) short hbuf[2][2][NB][72];

    // --- stage W_hh A-fragments (A[m=l15][k=quad*8+j], rows = gate*64+16w+m) ---
    bf16x8 Ahi[3][2], Alo[3][2];
#pragma unroll
    for (int g = 0; g < 3; ++g) {
        const int row = g * 64 + 16 * w + l15;
#pragma unroll
        for (int kh = 0; kh < 2; ++kh) {
            if (isbf) {
                const __hip_bfloat16* wr = (const __hip_bfloat16*)w_hh_raw
                                         + row * HID + kh * 32 + quad * 8;
                Ahi[g][kh] = *reinterpret_cast<const bf16x8*>(wr);
                short8 z = {0, 0, 0, 0, 0, 0, 0, 0};
                Alo[g][kh] = __builtin_bit_cast(bf16x8, z);
            } else {
                const float* wr = (const float*)w_hh_raw + row * HID + kh * 32 + quad * 8;
                floatx4 f0 = *reinterpret_cast<const floatx4*>(wr);
                floatx4 f1 = *reinterpret_cast<const floatx4*>(wr + 4);
                short8 hi, lo;
#pragma unroll
                for (int j = 0; j < 4; ++j) {
                    hi[j]     = f2bf_bits(f0[j]);
                    lo[j]     = f2bf_bits(f0[j] - bfbits2f(hi[j]));
                    hi[4 + j] = f2bf_bits(f1[j]);
                    lo[4 + j] = f2bf_bits(f1[j] - bfbits2f(hi[4 + j]));
                }
                Ahi[g][kh] = __builtin_bit_cast(bf16x8, hi);
                Alo[g][kh] = __builtin_bit_cast(bf16x8, lo);
            }
        }
    }

    // --- per-lane biases for the 4 owned units ---
    floatx4 bhr, bhz, bhn;
#pragma unroll
    for (int i = 0; i < 4; ++i) {
        const int u = 16 * w + quad * 4 + i;
        if (isbf) {
            const __hip_bfloat16* bb = (const __hip_bfloat16*)b_hh_raw;
            bhr[i] = bf2f(bb[u]); bhz[i] = bf2f(bb[64 + u]); bhn[i] = bf2f(bb[128 + u]);
        } else {
            const float* bb = (const float*)b_hh_raw;
            bhr[i] = bb[u]; bhz[i] = bb[64 + u]; bhn[i] = bb[128 + u];
        }
    }

    // --- x inputs for s=0 (one float4 per gate per lane) ---
    const int xoff = l15 * HID + 16 * w + quad * 4;
    floatx4 xv0 = *reinterpret_cast<const floatx4*>(xpt + (0 * 3 + 0) * NB * HID + xoff);
    floatx4 xv1 = *reinterpret_cast<const floatx4*>(xpt + (0 * 3 + 1) * NB * HID + xoff);
    floatx4 xv2 = *reinterpret_cast<const floatx4*>(xpt + (0 * 3 + 2) * NB * HID + xoff);

    // --- h state (4 owned units) + zero B-fragments (h0 = 0) ---
    floatx4 hreg = {0.f, 0.f, 0.f, 0.f};
    short8 z8 = {0, 0, 0, 0, 0, 0, 0, 0};
    bf16x8 Bh0 = __builtin_bit_cast(bf16x8, z8), Bh1 = Bh0, Bl0 = Bh0, Bl1 = Bh0;

    const floatx4 zero4 = {0.f, 0.f, 0.f, 0.f};

    for (int s = 0; s < NS; ++s) {
        // hp = W_hh . H   (split products: hi*hi + hi*lo [+ lo*hi if fp32 W])
        floatx4 ar = __builtin_amdgcn_mfma_f32_16x16x32_bf16(Ahi[0][0], Bh0, zero4, 0, 0, 0);
        floatx4 az = __builtin_amdgcn_mfma_f32_16x16x32_bf16(Ahi[1][0], Bh0, zero4, 0, 0, 0);
        floatx4 an = __builtin_amdgcn_mfma_f32_16x16x32_bf16(Ahi[2][0], Bh0, zero4, 0, 0, 0);
        ar = __builtin_amdgcn_mfma_f32_16x16x32_bf16(Ahi[0][1], Bh1, ar, 0, 0, 0);
        az = __builtin_amdgcn_mfma_f32_16x16x32_bf16(Ahi[1][1], Bh1, az, 0, 0, 0);
        an = __builtin_amdgcn_mfma_f32_16x16x32_bf16(Ahi[2][1], Bh1, an, 0, 0, 0);
        ar = __builtin_amdgcn_mfma_f32_16x16x32_bf16(Ahi[0][0], Bl0, ar, 0, 0, 0);
        az = __builtin_amdgcn_mfma_f32_16x16x32_bf16(Ahi[1][0], Bl0, az, 0, 0, 0);
        an = __builtin_amdgcn_mfma_f32_16x16x32_bf16(Ahi[2][0], Bl0, an, 0, 0, 0);
        ar = __builtin_amdgcn_mfma_f32_16x16x32_bf16(Ahi[0][1], Bl1, ar, 0, 0, 0);
        az = __builtin_amdgcn_mfma_f32_16x16x32_bf16(Ahi[1][1], Bl1, az, 0, 0, 0);
        an = __builtin_amdgcn_mfma_f32_16x16x32_bf16(Ahi[2][1], Bl1, an, 0, 0, 0);
        if (!isbf) {
            ar = __builtin_amdgcn_mfma_f32_16x16x32_bf16(Alo[0][0], Bh0, ar, 0, 0, 0);
            az = __builtin_amdgcn_mfma_f32_16x16x32_bf16(Alo[1][0], Bh0, az, 0, 0, 0);
            an = __builtin_amdgcn_mfma_f32_16x16x32_bf16(Alo[2][0], Bh0, an, 0, 0, 0);
            ar = __builtin_amdgcn_mfma_f32_16x16x32_bf16(Alo[0][1], Bh1, ar, 0, 0, 0);
            az = __builtin_amdgcn_mfma_f32_16x16x32_bf16(Alo[1][1], Bh1, az, 0, 0, 0);
            an = __builtin_amdgcn_mfma_f32_16x16x32_bf16(Alo[2][1], Bh1, an, 0, 0, 0);
        }

        // gates + h update (4 owned units)
        short4v hi4, lo4;
#pragma unroll
        for (int i = 0; i < 4; ++i) {
            const float r = __fdividef(1.f, 1.f + __expf(-(xv0[i] + ar[i] + bhr[i])));
            const float z = __fdividef(1.f, 1.f + __expf(-(xv1[i] + az[i] + bhz[i])));
            const float n = __fdividef(2.f, 1.f + __expf(-2.f * (xv2[i] + r * (an[i] + bhn[i])))) - 1.f;
            const float h = (1.f - z) * n + z * hreg[i];
            hreg[i] = h;
            hi4[i] = f2bf_bits(h);
            lo4[i] = f2bf_bits(h - bfbits2f(hi4[i]));
        }

        // hs output (bf16 hi part), coalesced 8B per lane
        *reinterpret_cast<short4v*>(
            (short*)hs + ((size_t)l15 * NS + s) * HID + 16 * w + quad * 4) = hi4;

        // redistribute h for next step's B-fragments
        const int nb = (s + 1) & 1;
        *reinterpret_cast<short4v*>(&hbuf[nb][0][l15][16 * w + quad * 4]) = hi4;
        *reinterpret_cast<short4v*>(&hbuf[nb][1][l15][16 * w + quad * 4]) = lo4;

        asm volatile("s_waitcnt lgkmcnt(0)" ::: "memory");  // ds_writes retire
        __builtin_amdgcn_s_barrier();

        if (s + 1 < NS) {
            const short* hb = &hbuf[nb][0][l15][0];
            const short* lb = &hbuf[nb][1][l15][0];
            Bh0 = *reinterpret_cast<const bf16x8*>(hb + quad * 8);
            Bh1 = *reinterpret_cast<const bf16x8*>(hb + 32 + quad * 8);
            Bl0 = *reinterpret_cast<const bf16x8*>(lb + quad * 8);
            Bl1 = *reinterpret_cast<const bf16x8*>(lb + 32 + quad * 8);
            // prefetch next step's x (consumed after next MFMA block)
            const float* xs = xpt + (size_t)(s + 1) * 3 * NB * HID;
            xv0 = *reinterpret_cast<const floatx4*>(xs + 0 * NB * HID + xoff);
            xv1 = *reinterpret_cast<const floatx4*>(xs + 1 * NB * HID + xoff);
            xv2 = *reinterpret_cast<const floatx4*>(xs + 2 * NB * HID + xoff);
        }
    }
}

// ---------------------------------------------------------------------------
// K3: out[m][v] = sum_k hs[m][k] * w_out[v][k] + b_out[v].
// mfma_f32_16x16x32_bf16; block = 4 waves, each wave does 16(M)x64(N).
// Grid: x = mtile (fast), y = ncb -> consecutive blocks share a w_out slice.
// Stores staged through LDS -> full-line-covered 256B row writes.
// ---------------------------------------------------------------------------
__global__ __launch_bounds__(256) void k_logits(
    const __hip_bfloat16* __restrict__ hs,
    const void* __restrict__ w_out_raw,
    const void* __restrict__ b_out_raw,
    void* __restrict__ out_raw)
{
    const bool isbf = detect_bf16(w_out_raw);
    const int mtile = blockIdx.x;            // 0..255 (16 rows each)  [fast dim]
    const int ncb   = blockIdx.y;            // 0..124 (256 cols each)
    const int wave  = threadIdx.x >> 6;      // 0..3
    const int lane  = threadIdx.x & 63;
    const int quad  = lane >> 4;
    const int l15   = lane & 15;

    __shared__ float tile[4][16][68];

    const __hip_bfloat16* arow = hs + (mtile * 16 + l15) * HID;
    const bf16x8 a0 = *reinterpret_cast<const bf16x8*>(arow + quad * 8);
    const bf16x8 a1 = *reinterpret_cast<const bf16x8*>(arow + 32 + quad * 8);

    const int ncol_wave = ncb * 256 + wave * 64;
#pragma unroll
    for (int t = 0; t < 4; ++t) {
        const int ncol = ncol_wave + t * 16;
        bf16x8 b0, b1;
        if (isbf) {
            const __hip_bfloat16* brow = (const __hip_bfloat16*)w_out_raw + (ncol + l15) * HID;
            b0 = *reinterpret_cast<const bf16x8*>(brow + quad * 8);
            b1 = *reinterpret_cast<const bf16x8*>(brow + 32 + quad * 8);
        } else {
            const float* browf = (const float*)w_out_raw + (ncol + l15) * HID;
            floatx4 f0 = *reinterpret_cast<const floatx4*>(browf + quad * 8);
            floatx4 f1 = *reinterpret_cast<const floatx4*>(browf + quad * 8 + 4);
            floatx4 f2 = *reinterpret_cast<const floatx4*>(browf + 32 + quad * 8);
            floatx4 f3 = *reinterpret_cast<const floatx4*>(browf + 32 + quad * 8 + 4);
            short8 s0, s1;
#pragma unroll
            for (int j = 0; j < 4; ++j) {
                s0[j] = f2bf_bits(f0[j]); s0[4 + j] = f2bf_bits(f1[j]);
                s1[j] = f2bf_bits(f2[j]); s1[4 + j] = f2bf_bits(f3[j]);
            }
            b0 = __builtin_bit_cast(bf16x8, s0);
            b1 = __builtin_bit_cast(bf16x8, s1);
        }

        floatx4 acc = {0.f, 0.f, 0.f, 0.f};
        acc = __builtin_amdgcn_mfma_f32_16x16x32_bf16(a0, b0, acc, 0, 0, 0);
        acc = __builtin_amdgcn_mfma_f32_16x16x32_bf16(a1, b1, acc, 0, 0, 0);

        const float bias = isbf ? bf2f(((const __hip_bfloat16*)b_out_raw)[ncol + l15])
                                : ((const float*)b_out_raw)[ncol + l15];
#pragma unroll
        for (int i = 0; i < 4; ++i)
            tile[wave][quad * 4 + i][t * 16 + l15] = acc[i] + bias;
    }
    __syncthreads();

    if (isbf) {
        short* outb = (short*)out_raw;
#pragma unroll
        for (int p = 0; p < 4; ++p) {
            const int row = p * 4 + quad;
            const float* src = &tile[wave][row][l15 * 4];
            short4v u;
#pragma unroll
            for (int jj = 0; jj < 4; ++jj) u[jj] = f2bf_bits(src[jj]);
            *reinterpret_cast<short4v*>(
                outb + (size_t)(mtile * 16 + row) * VOCAB + ncol_wave + l15 * 4) = u;
        }
    } else {
        float* outf = (float*)out_raw;
#pragma unroll
        for (int p = 0; p < 4; ++p) {
            const int row = p * 4 + quad;
            floatx4 v = *reinterpret_cast<const floatx4*>(&tile[wave][row][l15 * 4]);
            *reinterpret_cast<floatx4*>(
                outf + (size_t)(mtile * 16 + row) * VOCAB + ncol_wave + l15 * 4) = v;
        }
    }
}

// ---------------------------------------------------------------------------
extern "C" void kernel_launch(void* const* d_in, const int* in_sizes, int n_in,
                              void* d_out, int out_size, void* d_ws, size_t ws_size,
                              hipStream_t stream)
{
    const int*  tokens = (const int*)d_in[0];
    const void* emb    = d_in[1];
    const void* w_ih   = d_in[2];
    const void* w_hh   = d_in[3];
    const void* b_ih   = d_in[4];
    const void* b_hh   = d_in[5];
    const void* w_out  = d_in[6];
    const void* b_out  = d_in[7];

    // xpt scratch (3 MiB, layout [s][gate][b][u]) lives in d_out's head; it is
    // consumed by k_gru_scan before k_logits overwrites all of d_out.
    float* xpt = (float*)d_out;
    __hip_bfloat16* hs = (__hip_bfloat16*)d_ws;

    k_embed_proj_t<<<NS, G3, 0, stream>>>(tokens, emb, w_ih, b_ih, xpt);
    k_gru_scan<<<1, 256, 0, stream>>>(xpt, w_hh, b_hh, hs);
    dim3 grid3((NB * NS) / 16, VOCAB / 256);   // x = mtile (fast), y = ncb
    k_logits<<<grid3, 256, 0, stream>>>(hs, w_out, b_out, d_out);
}

// Round 4
// 972.120 us; speedup vs baseline: 1.0217x; 1.0217x over previous
//
#include <hip/hip_runtime.h>
#include <hip/hip_bf16.h>

#define VOCAB 32000
#define EMB   64
#define HID   64
#define NB    16
#define NS    256
#define G3    192   // 3*HID

typedef __bf16 bf16x8  __attribute__((ext_vector_type(8)));
typedef short  short8  __attribute__((ext_vector_type(8)));
typedef short  short4v __attribute__((ext_vector_type(4)));
typedef float  floatx4 __attribute__((ext_vector_type(4)));

__device__ __forceinline__ float bf2f(__hip_bfloat16 v) { return __bfloat162float(v); }

// RNE fp32 -> bf16 bit pattern (no NaN inputs possible here)
__device__ __forceinline__ short f2bf_bits(float f) {
    unsigned int u = __float_as_uint(f);
    unsigned int r = (u + 0x7FFFu + ((u >> 16) & 1u)) >> 16;
    return (short)r;
}

// bf16 bit pattern -> float
__device__ __forceinline__ float bfbits2f(short b) {
    return __uint_as_float(((unsigned int)(unsigned short)b) << 16);
}

// Runtime dtype detection: true if the array at p holds bf16 data, false if fp32.
__device__ __forceinline__ bool detect_bf16(const void* p) {
    const unsigned int* w = (const unsigned int*)p;
    unsigned int word = w[threadIdx.x & 63];
    unsigned int e = (word >> 7) & 0xFFu;
    int pred = (e >= 115u) && (e <= 130u);
    unsigned long long m = __ballot(pred);
    return __popcll(m) > 32;
}

// ---------------------------------------------------------------------------
// K1: xpt[s][gate][b][u] = sum_e emb[tok[b][s]][e] * w_ih[gate*64+u][e] + b_ih
// Transposed layout so K2's MFMA lanes read their gate inputs as one float4.
// ---------------------------------------------------------------------------
__global__ __launch_bounds__(G3) void k_embed_proj_t(
    const int* __restrict__ tokens,
    const void* __restrict__ emb_raw,
    const void* __restrict__ w_ih_raw,
    const void* __restrict__ b_ih_raw,
    float* __restrict__ xpt)
{
    const bool isbf = detect_bf16(w_ih_raw);
    const int s   = blockIdx.x;
    const int tid = threadIdx.x;

    __shared__ int   tok_s[NB];
    __shared__ float e_s[NB][EMB];

    if (tid < NB) tok_s[tid] = tokens[tid * NS + s];
    __syncthreads();
    for (int idx = tid; idx < NB * EMB; idx += G3) {
        const int b = idx >> 6, e = idx & 63;
        const int t = tok_s[b];
        e_s[b][e] = isbf ? bf2f(((const __hip_bfloat16*)emb_raw)[t * EMB + e])
                         : ((const float*)emb_raw)[t * EMB + e];
    }
    __syncthreads();

    float wf[EMB];
    if (isbf) {
        const __hip_bfloat16* wrow = (const __hip_bfloat16*)w_ih_raw + tid * EMB;
#pragma unroll
        for (int k0 = 0; k0 < EMB; k0 += 8) {
            bf16x8 wv = *reinterpret_cast<const bf16x8*>(wrow + k0);
#pragma unroll
            for (int j = 0; j < 8; ++j) wf[k0 + j] = (float)wv[j];
        }
    } else {
        const float* wrow = (const float*)w_ih_raw + tid * EMB;
#pragma unroll
        for (int k0 = 0; k0 < EMB; k0 += 4) {
            floatx4 wv = *reinterpret_cast<const floatx4*>(wrow + k0);
#pragma unroll
            for (int j = 0; j < 4; ++j) wf[k0 + j] = wv[j];
        }
    }
    const float bias = isbf ? bf2f(((const __hip_bfloat16*)b_ih_raw)[tid])
                            : ((const float*)b_ih_raw)[tid];

    const int gam = tid >> 6;       // gate 0..2 (r,z,n)
    const int u   = tid & 63;       // unit
    float* orow = xpt + ((size_t)(s * 3 + gam) * NB) * HID + u;
    for (int b = 0; b < NB; ++b) {
        float acc = bias;
#pragma unroll
        for (int k0 = 0; k0 < EMB; k0 += 4) {
            floatx4 e4 = *reinterpret_cast<const floatx4*>(&e_s[b][k0]);
            acc += e4[0] * wf[k0] + e4[1] * wf[k0 + 1]
                 + e4[2] * wf[k0 + 2] + e4[3] * wf[k0 + 3];
        }
        orow[b * HID] = acc;   // lanes u=0..63 contiguous -> 256B coalesced
    }
}

// ---------------------------------------------------------------------------
// K2: GRU scan via MFMA, one block / 4 waves, per step:
//   hp(192x16) = W_hh(192x64) . H(64x16), split-bf16 for fp32 accuracy.
// CHANGE vs R3: xv loads are prefetched DEPTH-2 (issued at top of step s for
// step s+2, statically rotated registers) so the ~600-900 cy cold-L2/L3
// latency of fresh xpt lines fully hides under two iterations of MFMA+gates.
// One lgkmcnt-only barrier per step (no vmcnt drain -> loads stay in flight).
// ---------------------------------------------------------------------------
__global__ __launch_bounds__(256, 1) void k_gru_scan(
    const float* __restrict__ xpt,
    const void* __restrict__ w_hh_raw,
    const void* __restrict__ b_hh_raw,
    __hip_bfloat16* __restrict__ hs)
{
    const bool isbf = detect_bf16(w_hh_raw);
    const int tid  = threadIdx.x;
    const int w    = tid >> 6;       // wave 0..3 -> unit slab 16w
    const int lane = tid & 63;
    const int quad = lane >> 4;
    const int l15  = lane & 15;      // batch

    // h double-buffer: [buf][hi/lo][batch][unit padded to 72]
    __shared__ __align__(16) short hbuf[2][2][NB][72];

    // --- stage W_hh A-fragments (A[m=l15][k=quad*8+j], rows = gate*64+16w+m) ---
    bf16x8 Ahi[3][2], Alo[3][2];
#pragma unroll
    for (int g = 0; g < 3; ++g) {
        const int row = g * 64 + 16 * w + l15;
#pragma unroll
        for (int kh = 0; kh < 2; ++kh) {
            if (isbf) {
                const __hip_bfloat16* wr = (const __hip_bfloat16*)w_hh_raw
                                         + row * HID + kh * 32 + quad * 8;
                Ahi[g][kh] = *reinterpret_cast<const bf16x8*>(wr);
                short8 z = {0, 0, 0, 0, 0, 0, 0, 0};
                Alo[g][kh] = __builtin_bit_cast(bf16x8, z);
            } else {
                const float* wr = (const float*)w_hh_raw + row * HID + kh * 32 + quad * 8;
                floatx4 f0 = *reinterpret_cast<const floatx4*>(wr);
                floatx4 f1 = *reinterpret_cast<const floatx4*>(wr + 4);
                short8 hi, lo;
#pragma unroll
                for (int j = 0; j < 4; ++j) {
                    hi[j]     = f2bf_bits(f0[j]);
                    lo[j]     = f2bf_bits(f0[j] - bfbits2f(hi[j]));
                    hi[4 + j] = f2bf_bits(f1[j]);
                    lo[4 + j] = f2bf_bits(f1[j] - bfbits2f(hi[4 + j]));
                }
                Ahi[g][kh] = __builtin_bit_cast(bf16x8, hi);
                Alo[g][kh] = __builtin_bit_cast(bf16x8, lo);
            }
        }
    }

    // --- per-lane biases for the 4 owned units ---
    floatx4 bhr, bhz, bhn;
#pragma unroll
    for (int i = 0; i < 4; ++i) {
        const int u = 16 * w + quad * 4 + i;
        if (isbf) {
            const __hip_bfloat16* bb = (const __hip_bfloat16*)b_hh_raw;
            bhr[i] = bf2f(bb[u]); bhz[i] = bf2f(bb[64 + u]); bhn[i] = bf2f(bb[128 + u]);
        } else {
            const float* bb = (const float*)b_hh_raw;
            bhr[i] = bb[u]; bhz[i] = bb[64 + u]; bhn[i] = bb[128 + u];
        }
    }

    // --- xv register pipeline: cur (s), nxt (s+1), pf (s+2) ---
    const int xoff = l15 * HID + 16 * w + quad * 4;
    const floatx4 zero4 = {0.f, 0.f, 0.f, 0.f};
    floatx4 xc0 = *reinterpret_cast<const floatx4*>(xpt + (0 * 3 + 0) * NB * HID + xoff);
    floatx4 xc1 = *reinterpret_cast<const floatx4*>(xpt + (0 * 3 + 1) * NB * HID + xoff);
    floatx4 xc2 = *reinterpret_cast<const floatx4*>(xpt + (0 * 3 + 2) * NB * HID + xoff);
    floatx4 xn0 = *reinterpret_cast<const floatx4*>(xpt + (1 * 3 + 0) * NB * HID + xoff);
    floatx4 xn1 = *reinterpret_cast<const floatx4*>(xpt + (1 * 3 + 1) * NB * HID + xoff);
    floatx4 xn2 = *reinterpret_cast<const floatx4*>(xpt + (1 * 3 + 2) * NB * HID + xoff);

    // --- h state (4 owned units) + zero B-fragments (h0 = 0) ---
    floatx4 hreg = {0.f, 0.f, 0.f, 0.f};
    short8 z8 = {0, 0, 0, 0, 0, 0, 0, 0};
    bf16x8 Bh0 = __builtin_bit_cast(bf16x8, z8), Bh1 = Bh0, Bl0 = Bh0, Bl1 = Bh0;

    for (int s = 0; s < NS; ++s) {
        // issue depth-2 prefetch FIRST: loads for step s+2 fly while this
        // step's MFMAs + gates + barrier and the next step's MFMAs execute.
        floatx4 pf0 = zero4, pf1 = zero4, pf2 = zero4;
        if (s + 2 < NS) {
            const float* xs = xpt + (size_t)(s + 2) * 3 * NB * HID;
            pf0 = *reinterpret_cast<const floatx4*>(xs + 0 * NB * HID + xoff);
            pf1 = *reinterpret_cast<const floatx4*>(xs + 1 * NB * HID + xoff);
            pf2 = *reinterpret_cast<const floatx4*>(xs + 2 * NB * HID + xoff);
        }

        // hp = W_hh . H   (split products: Ahi*Bh + Ahi*Bl [+ Alo*Bh if fp32])
        floatx4 ar = __builtin_amdgcn_mfma_f32_16x16x32_bf16(Ahi[0][0], Bh0, zero4, 0, 0, 0);
        floatx4 az = __builtin_amdgcn_mfma_f32_16x16x32_bf16(Ahi[1][0], Bh0, zero4, 0, 0, 0);
        floatx4 an = __builtin_amdgcn_mfma_f32_16x16x32_bf16(Ahi[2][0], Bh0, zero4, 0, 0, 0);
        ar = __builtin_amdgcn_mfma_f32_16x16x32_bf16(Ahi[0][1], Bh1, ar, 0, 0, 0);
        az = __builtin_amdgcn_mfma_f32_16x16x32_bf16(Ahi[1][1], Bh1, az, 0, 0, 0);
        an = __builtin_amdgcn_mfma_f32_16x16x32_bf16(Ahi[2][1], Bh1, an, 0, 0, 0);
        ar = __builtin_amdgcn_mfma_f32_16x16x32_bf16(Ahi[0][0], Bl0, ar, 0, 0, 0);
        az = __builtin_amdgcn_mfma_f32_16x16x32_bf16(Ahi[1][0], Bl0, az, 0, 0, 0);
        an = __builtin_amdgcn_mfma_f32_16x16x32_bf16(Ahi[2][0], Bl0, an, 0, 0, 0);
        ar = __builtin_amdgcn_mfma_f32_16x16x32_bf16(Ahi[0][1], Bl1, ar, 0, 0, 0);
        az = __builtin_amdgcn_mfma_f32_16x16x32_bf16(Ahi[1][1], Bl1, az, 0, 0, 0);
        an = __builtin_amdgcn_mfma_f32_16x16x32_bf16(Ahi[2][1], Bl1, an, 0, 0, 0);
        if (!isbf) {
            ar = __builtin_amdgcn_mfma_f32_16x16x32_bf16(Alo[0][0], Bh0, ar, 0, 0, 0);
            az = __builtin_amdgcn_mfma_f32_16x16x32_bf16(Alo[1][0], Bh0, az, 0, 0, 0);
            an = __builtin_amdgcn_mfma_f32_16x16x32_bf16(Alo[2][0], Bh0, an, 0, 0, 0);
            ar = __builtin_amdgcn_mfma_f32_16x16x32_bf16(Alo[0][1], Bh1, ar, 0, 0, 0);
            az = __builtin_amdgcn_mfma_f32_16x16x32_bf16(Alo[1][1], Bh1, az, 0, 0, 0);
            an = __builtin_amdgcn_mfma_f32_16x16x32_bf16(Alo[2][1], Bh1, an, 0, 0, 0);
        }

        // gates + h update (4 owned units)
        short4v hi4, lo4;
#pragma unroll
        for (int i = 0; i < 4; ++i) {
            const float r = __fdividef(1.f, 1.f + __expf(-(xc0[i] + ar[i] + bhr[i])));
            const float z = __fdividef(1.f, 1.f + __expf(-(xc1[i] + az[i] + bhz[i])));
            const float n = __fdividef(2.f, 1.f + __expf(-2.f * (xc2[i] + r * (an[i] + bhn[i])))) - 1.f;
            const float h = (1.f - z) * n + z * hreg[i];
            hreg[i] = h;
            hi4[i] = f2bf_bits(h);
            lo4[i] = f2bf_bits(h - bfbits2f(hi4[i]));
        }

        // hs output (bf16 hi part), 8B per lane
        *reinterpret_cast<short4v*>(
            (short*)hs + ((size_t)l15 * NS + s) * HID + 16 * w + quad * 4) = hi4;

        // redistribute h for next step's B-fragments
        const int nb = (s + 1) & 1;
        *reinterpret_cast<short4v*>(&hbuf[nb][0][l15][16 * w + quad * 4]) = hi4;
        *reinterpret_cast<short4v*>(&hbuf[nb][1][l15][16 * w + quad * 4]) = lo4;

        asm volatile("s_waitcnt lgkmcnt(0)" ::: "memory");  // ds_writes retire (vmcnt untouched)
        __builtin_amdgcn_s_barrier();

        if (s + 1 < NS) {
            const short* hb = &hbuf[nb][0][l15][0];
            const short* lb = &hbuf[nb][1][l15][0];
            Bh0 = *reinterpret_cast<const bf16x8*>(hb + quad * 8);
            Bh1 = *reinterpret_cast<const bf16x8*>(hb + 32 + quad * 8);
            Bl0 = *reinterpret_cast<const bf16x8*>(lb + quad * 8);
            Bl1 = *reinterpret_cast<const bf16x8*>(lb + 32 + quad * 8);
        }

        // rotate the xv pipeline (pure register moves, all static)
        xc0 = xn0; xc1 = xn1; xc2 = xn2;
        xn0 = pf0; xn1 = pf1; xn2 = pf2;
    }
}

// ---------------------------------------------------------------------------
// K3: out[m][v] = sum_k hs[m][k] * w_out[v][k] + b_out[v].
// Grid: x = mtile (fast), y = ncb -> consecutive blocks share a w_out slice.
// Stores staged through LDS then written with NONTEMPORAL float4 stores:
// the 524 MB output is write-once, so streaming it past L2 keeps the w_out
// slice resident per XCD and removes dirty-writeback pressure.
// ---------------------------------------------------------------------------
__global__ __launch_bounds__(256) void k_logits(
    const __hip_bfloat16* __restrict__ hs,
    const void* __restrict__ w_out_raw,
    const void* __restrict__ b_out_raw,
    void* __restrict__ out_raw)
{
    const bool isbf = detect_bf16(w_out_raw);
    const int mtile = blockIdx.x;            // 0..255 (16 rows each)  [fast dim]
    const int ncb   = blockIdx.y;            // 0..124 (256 cols each)
    const int wave  = threadIdx.x >> 6;      // 0..3
    const int lane  = threadIdx.x & 63;
    const int quad  = lane >> 4;
    const int l15   = lane & 15;

    __shared__ float tile[4][16][68];

    const __hip_bfloat16* arow = hs + (mtile * 16 + l15) * HID;
    const bf16x8 a0 = *reinterpret_cast<const bf16x8*>(arow + quad * 8);
    const bf16x8 a1 = *reinterpret_cast<const bf16x8*>(arow + 32 + quad * 8);

    const int ncol_wave = ncb * 256 + wave * 64;
#pragma unroll
    for (int t = 0; t < 4; ++t) {
        const int ncol = ncol_wave + t * 16;
        bf16x8 b0, b1;
        if (isbf) {
            const __hip_bfloat16* brow = (const __hip_bfloat16*)w_out_raw + (ncol + l15) * HID;
            b0 = *reinterpret_cast<const bf16x8*>(brow + quad * 8);
            b1 = *reinterpret_cast<const bf16x8*>(brow + 32 + quad * 8);
        } else {
            const float* browf = (const float*)w_out_raw + (ncol + l15) * HID;
            floatx4 f0 = *reinterpret_cast<const floatx4*>(browf + quad * 8);
            floatx4 f1 = *reinterpret_cast<const floatx4*>(browf + quad * 8 + 4);
            floatx4 f2 = *reinterpret_cast<const floatx4*>(browf + 32 + quad * 8);
            floatx4 f3 = *reinterpret_cast<const floatx4*>(browf + 32 + quad * 8 + 4);
            short8 s0, s1;
#pragma unroll
            for (int j = 0; j < 4; ++j) {
                s0[j] = f2bf_bits(f0[j]); s0[4 + j] = f2bf_bits(f1[j]);
                s1[j] = f2bf_bits(f2[j]); s1[4 + j] = f2bf_bits(f3[j]);
            }
            b0 = __builtin_bit_cast(bf16x8, s0);
            b1 = __builtin_bit_cast(bf16x8, s1);
        }

        floatx4 acc = {0.f, 0.f, 0.f, 0.f};
        acc = __builtin_amdgcn_mfma_f32_16x16x32_bf16(a0, b0, acc, 0, 0, 0);
        acc = __builtin_amdgcn_mfma_f32_16x16x32_bf16(a1, b1, acc, 0, 0, 0);

        const float bias = isbf ? bf2f(((const __hip_bfloat16*)b_out_raw)[ncol + l15])
                                : ((const float*)b_out_raw)[ncol + l15];
#pragma unroll
        for (int i = 0; i < 4; ++i)
            tile[wave][quad * 4 + i][t * 16 + l15] = acc[i] + bias;
    }
    __syncthreads();

    // Coalesced nontemporal writeback: quad q writes row p*4+q, 64 lanes
    // cover 256 B contiguous per row -> full cache lines, streamed past L2.
    if (isbf) {
        short* outb = (short*)out_raw;
#pragma unroll
        for (int p = 0; p < 4; ++p) {
            const int row = p * 4 + quad;
            const float* src = &tile[wave][row][l15 * 4];
            short4v u;
#pragma unroll
            for (int jj = 0; jj < 4; ++jj) u[jj] = f2bf_bits(src[jj]);
            __builtin_nontemporal_store(u, reinterpret_cast<short4v*>(
                outb + (size_t)(mtile * 16 + row) * VOCAB + ncol_wave + l15 * 4));
        }
    } else {
        float* outf = (float*)out_raw;
#pragma unroll
        for (int p = 0; p < 4; ++p) {
            const int row = p * 4 + quad;
            floatx4 v = *reinterpret_cast<const floatx4*>(&tile[wave][row][l15 * 4]);
            __builtin_nontemporal_store(v, reinterpret_cast<floatx4*>(
                outf + (size_t)(mtile * 16 + row) * VOCAB + ncol_wave + l15 * 4));
        }
    }
}

// ---------------------------------------------------------------------------
extern "C" void kernel_launch(void* const* d_in, const int* in_sizes, int n_in,
                              void* d_out, int out_size, void* d_ws, size_t ws_size,
                              hipStream_t stream)
{
    const int*  tokens = (const int*)d_in[0];
    const void* emb    = d_in[1];
    const void* w_ih   = d_in[2];
    const void* w_hh   = d_in[3];
    const void* b_ih   = d_in[4];
    const void* b_hh   = d_in[5];
    const void* w_out  = d_in[6];
    const void* b_out  = d_in[7];

    // xpt scratch (3 MiB, layout [s][gate][b][u]) lives in d_out's head; it is
    // consumed by k_gru_scan before k_logits overwrites all of d_out.
    float* xpt = (float*)d_out;
    __hip_bfloat16* hs = (__hip_bfloat16*)d_ws;

    k_embed_proj_t<<<NS, G3, 0, stream>>>(tokens, emb, w_ih, b_ih, xpt);
    k_gru_scan<<<1, 256, 0, stream>>>(xpt, w_hh, b_hh, hs);
    dim3 grid3((NB * NS) / 16, VOCAB / 256);   // x = mtile (fast), y = ncb
    k_logits<<<grid3, 256, 0, stream>>>(hs, w_out, b_out, d_out);
}

// Round 5
// 746.087 us; speedup vs baseline: 1.3312x; 1.3030x over previous
//
#include <hip/hip_runtime.h>
#include <hip/hip_bf16.h>

#define VOCAB 32000
#define EMB   64
#define HID   64
#define NB    16
#define NS    256
#define G3    192   // 3*HID
#define MT    4     // mtiles per k_logits block (w_out reuse factor)

typedef __bf16 bf16x8  __attribute__((ext_vector_type(8)));
typedef short  short8  __attribute__((ext_vector_type(8)));
typedef short  short4v __attribute__((ext_vector_type(4)));
typedef float  floatx4 __attribute__((ext_vector_type(4)));
typedef float  floatx2 __attribute__((ext_vector_type(2)));

__device__ __forceinline__ float bf2f(__hip_bfloat16 v) { return __bfloat162float(v); }

// RNE fp32 -> bf16 bit pattern (no NaN inputs possible here)
__device__ __forceinline__ short f2bf_bits(float f) {
    unsigned int u = __float_as_uint(f);
    unsigned int r = (u + 0x7FFFu + ((u >> 16) & 1u)) >> 16;
    return (short)r;
}

// Runtime dtype detection: true if the array at p holds bf16 data, false if fp32.
__device__ __forceinline__ bool detect_bf16(const void* p) {
    const unsigned int* w = (const unsigned int*)p;
    unsigned int word = w[threadIdx.x & 63];
    unsigned int e = (word >> 7) & 0xFFu;
    int pred = (e >= 115u) && (e <= 130u);
    unsigned long long m = __ballot(pred);
    return __popcll(m) > 32;
}

// lane-broadcast of a float via v_readlane (result wave-uniform -> SGPR)
__device__ __forceinline__ float bcastf(float v, int l) {
    return __uint_as_float(__builtin_amdgcn_readlane(__float_as_uint(v), l));
}

// ---------------------------------------------------------------------------
// K1: xpt[s][gate][b][u] = sum_e emb[tok[b][s]][e] * w_ih[gate*64+u][e] + b_ih
// Transposed layout: K2's lanes (u contiguous) read 256B-coalesced rows.
// ---------------------------------------------------------------------------
__global__ __launch_bounds__(G3) void k_embed_proj_t(
    const int* __restrict__ tokens,
    const void* __restrict__ emb_raw,
    const void* __restrict__ w_ih_raw,
    const void* __restrict__ b_ih_raw,
    float* __restrict__ xpt)
{
    const bool isbf = detect_bf16(w_ih_raw);
    const int s   = blockIdx.x;
    const int tid = threadIdx.x;

    __shared__ int   tok_s[NB];
    __shared__ float e_s[NB][EMB];

    if (tid < NB) tok_s[tid] = tokens[tid * NS + s];
    __syncthreads();
    for (int idx = tid; idx < NB * EMB; idx += G3) {
        const int b = idx >> 6, e = idx & 63;
        const int t = tok_s[b];
        e_s[b][e] = isbf ? bf2f(((const __hip_bfloat16*)emb_raw)[t * EMB + e])
                         : ((const float*)emb_raw)[t * EMB + e];
    }
    __syncthreads();

    float wf[EMB];
    if (isbf) {
        const __hip_bfloat16* wrow = (const __hip_bfloat16*)w_ih_raw + tid * EMB;
#pragma unroll
        for (int k0 = 0; k0 < EMB; k0 += 8) {
            bf16x8 wv = *reinterpret_cast<const bf16x8*>(wrow + k0);
#pragma unroll
            for (int j = 0; j < 8; ++j) wf[k0 + j] = (float)wv[j];
        }
    } else {
        const float* wrow = (const float*)w_ih_raw + tid * EMB;
#pragma unroll
        for (int k0 = 0; k0 < EMB; k0 += 4) {
            floatx4 wv = *reinterpret_cast<const floatx4*>(wrow + k0);
#pragma unroll
            for (int j = 0; j < 4; ++j) wf[k0 + j] = wv[j];
        }
    }
    const float bias = isbf ? bf2f(((const __hip_bfloat16*)b_ih_raw)[tid])
                            : ((const float*)b_ih_raw)[tid];

    const int gam = tid >> 6;       // gate 0..2 (r,z,n)
    const int u   = tid & 63;       // unit
    float* orow = xpt + ((size_t)(s * 3 + gam) * NB) * HID + u;
    for (int b = 0; b < NB; ++b) {
        float acc = bias;
#pragma unroll
        for (int k0 = 0; k0 < EMB; k0 += 4) {
            floatx4 e4 = *reinterpret_cast<const floatx4*>(&e_s[b][k0]);
            acc += e4[0] * wf[k0] + e4[1] * wf[k0 + 1]
                 + e4[2] * wf[k0 + 2] + e4[3] * wf[k0 + 3];
        }
        orow[b * HID] = acc;   // lanes u=0..63 contiguous -> 256B coalesced
    }
}

// ---------------------------------------------------------------------------
// K2: sequential GRU scan — REVERTED to the best-measured scalar structure
// (R2: one wave per batch, float2 weights, batched readlanes) + depth-2
// register prefetch of the x-projections (issued at top of step s for s+2,
// statically rotated) so the cold-L2/L3 latency of fresh xpt lines hides
// under ~2 iterations of dot+gates.
// ---------------------------------------------------------------------------
__global__ __launch_bounds__(64, 1) void k_gru_scan(
    const float* __restrict__ xpt,
    const void* __restrict__ w_hh_raw,
    const void* __restrict__ b_hh_raw,
    __hip_bfloat16* __restrict__ hs)
{
    const bool isbf = detect_bf16(w_hh_raw);
    const int b = blockIdx.x;
    const int j = threadIdx.x;   // 0..63, owns hidden unit j

    floatx2 wr2[HID / 2], wz2[HID / 2], wn2[HID / 2];
    if (isbf) {
        const __hip_bfloat16* w = (const __hip_bfloat16*)w_hh_raw;
#pragma unroll
        for (int k0 = 0; k0 < HID; k0 += 8) {
            bf16x8 v0 = *reinterpret_cast<const bf16x8*>(w + (          j) * HID + k0);
            bf16x8 v1 = *reinterpret_cast<const bf16x8*>(w + (HID     + j) * HID + k0);
            bf16x8 v2 = *reinterpret_cast<const bf16x8*>(w + (2 * HID + j) * HID + k0);
#pragma unroll
            for (int t = 0; t < 4; ++t) {
                wr2[(k0 >> 1) + t] = (floatx2){(float)v0[2 * t], (float)v0[2 * t + 1]};
                wz2[(k0 >> 1) + t] = (floatx2){(float)v1[2 * t], (float)v1[2 * t + 1]};
                wn2[(k0 >> 1) + t] = (floatx2){(float)v2[2 * t], (float)v2[2 * t + 1]};
            }
        }
    } else {
        const float* w = (const float*)w_hh_raw;
#pragma unroll
        for (int k0 = 0; k0 < HID; k0 += 4) {
            floatx4 v0 = *reinterpret_cast<const floatx4*>(w + (          j) * HID + k0);
            floatx4 v1 = *reinterpret_cast<const floatx4*>(w + (HID     + j) * HID + k0);
            floatx4 v2 = *reinterpret_cast<const floatx4*>(w + (2 * HID + j) * HID + k0);
#pragma unroll
            for (int t = 0; t < 2; ++t) {
                wr2[(k0 >> 1) + t] = (floatx2){v0[2 * t], v0[2 * t + 1]};
                wz2[(k0 >> 1) + t] = (floatx2){v1[2 * t], v1[2 * t + 1]};
                wn2[(k0 >> 1) + t] = (floatx2){v2[2 * t], v2[2 * t + 1]};
            }
        }
    }

    float bhr, bhz, bhn;
    if (isbf) {
        const __hip_bfloat16* bb = (const __hip_bfloat16*)b_hh_raw;
        bhr = bf2f(bb[j]); bhz = bf2f(bb[HID + j]); bhn = bf2f(bb[2 * HID + j]);
    } else {
        const float* bb = (const float*)b_hh_raw;
        bhr = bb[j]; bhz = bb[HID + j]; bhn = bb[2 * HID + j];
    }

    // xpt layout: [s][gate][b][u] -> lanes u contiguous (256B coalesced)
    const float* xbase = xpt + (size_t)b * HID + j;
    // element (s, g) at xbase[((s*3+g)*NB)*HID]
#define XLD(s, g) xbase[((size_t)((s) * 3 + (g)) * NB) * HID]

    float xc0 = XLD(0, 0), xc1 = XLD(0, 1), xc2 = XLD(0, 2);
    float xn0 = XLD(1, 0), xn1 = XLD(1, 1), xn2 = XLD(1, 2);
    float h = 0.f;

    for (int s = 0; s < NS; ++s) {
        // depth-2 prefetch: loads for step s+2 fly across ~2 iterations
        float pf0 = 0.f, pf1 = 0.f, pf2 = 0.f;
        if (s + 2 < NS) {
            pf0 = XLD(s + 2, 0); pf1 = XLD(s + 2, 1); pf2 = XLD(s + 2, 2);
        }

        floatx2 ar0 = {0.f, 0.f}, ar1 = {0.f, 0.f};
        floatx2 az0 = {0.f, 0.f}, az1 = {0.f, 0.f};
        floatx2 an0 = {0.f, 0.f}, an1 = {0.f, 0.f};
#pragma unroll
        for (int kk = 0; kk < HID; kk += 16) {
            // batch 16 independent broadcasts -> SGPRs (pipelined)
            float hb[16];
#pragma unroll
            for (int t = 0; t < 16; ++t) hb[t] = bcastf(h, kk + t);
#pragma unroll
            for (int p = 0; p < 8; ++p) {
                const int w = (kk >> 1) + p;
                floatx2 hv;
                hv[0] = hb[2 * p];
                hv[1] = hb[2 * p + 1];
                if (p & 1) { ar1 += hv * wr2[w]; az1 += hv * wz2[w]; an1 += hv * wn2[w]; }
                else       { ar0 += hv * wr2[w]; az0 += hv * wz2[w]; an0 += hv * wn2[w]; }
            }
        }
        const float arf = (ar0[0] + ar0[1]) + (ar1[0] + ar1[1]);
        const float azf = (az0[0] + az0[1]) + (az1[0] + az1[1]);
        const float anf = (an0[0] + an0[1]) + (an1[0] + an1[1]);

        const float r = __fdividef(1.f, 1.f + __expf(-(xc0 + arf + bhr)));
        const float z = __fdividef(1.f, 1.f + __expf(-(xc1 + azf + bhz)));
        const float n = __fdividef(2.f, 1.f + __expf(-2.f * (xc2 + r * (anf + bhn)))) - 1.f;
        h = (1.f - z) * n + z * h;

        hs[((size_t)b * NS + s) * HID + j] = __float2bfloat16(h);

        // rotate the register pipeline (all static)
        xc0 = xn0; xc1 = xn1; xc2 = xn2;
        xn0 = pf0; xn1 = pf1; xn2 = pf2;
    }
#undef XLD
}

// ---------------------------------------------------------------------------
// K3: out[m][v] = sum_k hs[m][k] * w_out[v][k] + b_out[v].
// CHANGE: each block now processes MT=4 mtiles (64 rows) x 256 cols with the
// SAME in-register w_out B-fragments -> logical w_out traffic /4 (2.1 GB ->
// 525 MB); FETCH_SIZE should drop from ~1.0 GB to ~0.2-0.3 GB.
// Grid: x = mtile-group (fast), y = ncb -> consecutive blocks share a slice.
// Stores staged through LDS -> 256B-contiguous nontemporal row writes.
// ---------------------------------------------------------------------------
__global__ __launch_bounds__(256) void k_logits(
    const __hip_bfloat16* __restrict__ hs,
    const void* __restrict__ w_out_raw,
    const void* __restrict__ b_out_raw,
    void* __restrict__ out_raw)
{
    const bool isbf = detect_bf16(w_out_raw);
    const int mg    = blockIdx.x;            // 0..63  (4 mtiles = 64 rows each)
    const int ncb   = blockIdx.y;            // 0..124 (256 cols each)
    const int wave  = threadIdx.x >> 6;      // 0..3
    const int lane  = threadIdx.x & 63;
    const int quad  = lane >> 4;
    const int l15   = lane & 15;

    __shared__ float tile[4][16][68];

    const int ncol_wave = ncb * 256 + wave * 64;

    // --- load B-fragments + bias ONCE, reuse across MT mtiles ---
    bf16x8 B0[4], B1[4];
    float biasv[4];
#pragma unroll
    for (int t = 0; t < 4; ++t) {
        const int ncol = ncol_wave + t * 16;
        if (isbf) {
            const __hip_bfloat16* brow = (const __hip_bfloat16*)w_out_raw + (ncol + l15) * HID;
            B0[t] = *reinterpret_cast<const bf16x8*>(brow + quad * 8);
            B1[t] = *reinterpret_cast<const bf16x8*>(brow + 32 + quad * 8);
            biasv[t] = bf2f(((const __hip_bfloat16*)b_out_raw)[ncol + l15]);
        } else {
            const float* browf = (const float*)w_out_raw + (ncol + l15) * HID;
            floatx4 f0 = *reinterpret_cast<const floatx4*>(browf + quad * 8);
            floatx4 f1 = *reinterpret_cast<const floatx4*>(browf + quad * 8 + 4);
            floatx4 f2 = *reinterpret_cast<const floatx4*>(browf + 32 + quad * 8);
            floatx4 f3 = *reinterpret_cast<const floatx4*>(browf + 32 + quad * 8 + 4);
            short8 s0, s1;
#pragma unroll
            for (int jj = 0; jj < 4; ++jj) {
                s0[jj] = f2bf_bits(f0[jj]); s0[4 + jj] = f2bf_bits(f1[jj]);
                s1[jj] = f2bf_bits(f2[jj]); s1[4 + jj] = f2bf_bits(f3[jj]);
            }
            B0[t] = __builtin_bit_cast(bf16x8, s0);
            B1[t] = __builtin_bit_cast(bf16x8, s1);
            biasv[t] = ((const float*)b_out_raw)[ncol + l15];
        }
    }

#pragma unroll
    for (int mt = 0; mt < MT; ++mt) {
        const int mtile = mg * MT + mt;
        const __hip_bfloat16* arow = hs + (mtile * 16 + l15) * HID;
        const bf16x8 a0 = *reinterpret_cast<const bf16x8*>(arow + quad * 8);
        const bf16x8 a1 = *reinterpret_cast<const bf16x8*>(arow + 32 + quad * 8);

#pragma unroll
        for (int t = 0; t < 4; ++t) {
            floatx4 acc = {0.f, 0.f, 0.f, 0.f};
            acc = __builtin_amdgcn_mfma_f32_16x16x32_bf16(a0, B0[t], acc, 0, 0, 0);
            acc = __builtin_amdgcn_mfma_f32_16x16x32_bf16(a1, B1[t], acc, 0, 0, 0);
            // C layout: col = lane&15, row = quad*4 + i  ->  stage into LDS
#pragma unroll
            for (int i = 0; i < 4; ++i)
                tile[wave][quad * 4 + i][t * 16 + l15] = acc[i] + biasv[t];
        }
        __syncthreads();

        // Coalesced nontemporal writeback: quad q writes row p*4+q, 64 lanes
        // cover 256 B contiguous per row -> full cache lines past L2.
        if (isbf) {
            short* outb = (short*)out_raw;
#pragma unroll
            for (int p = 0; p < 4; ++p) {
                const int row = p * 4 + quad;
                const float* src = &tile[wave][row][l15 * 4];
                short4v u;
#pragma unroll
                for (int jj = 0; jj < 4; ++jj) u[jj] = f2bf_bits(src[jj]);
                __builtin_nontemporal_store(u, reinterpret_cast<short4v*>(
                    outb + (size_t)(mtile * 16 + row) * VOCAB + ncol_wave + l15 * 4));
            }
        } else {
            float* outf = (float*)out_raw;
#pragma unroll
            for (int p = 0; p < 4; ++p) {
                const int row = p * 4 + quad;
                floatx4 v = *reinterpret_cast<const floatx4*>(&tile[wave][row][l15 * 4]);
                __builtin_nontemporal_store(v, reinterpret_cast<floatx4*>(
                    outf + (size_t)(mtile * 16 + row) * VOCAB + ncol_wave + l15 * 4));
            }
        }
        __syncthreads();   // protect tile[] before next mt overwrites it
    }
}

// ---------------------------------------------------------------------------
extern "C" void kernel_launch(void* const* d_in, const int* in_sizes, int n_in,
                              void* d_out, int out_size, void* d_ws, size_t ws_size,
                              hipStream_t stream)
{
    const int*  tokens = (const int*)d_in[0];
    const void* emb    = d_in[1];
    const void* w_ih   = d_in[2];
    const void* w_hh   = d_in[3];
    const void* b_ih   = d_in[4];
    const void* b_hh   = d_in[5];
    const void* w_out  = d_in[6];
    const void* b_out  = d_in[7];

    // xpt scratch (3 MiB, layout [s][gate][b][u]) lives in d_out's head; it is
    // consumed by k_gru_scan before k_logits overwrites all of d_out.
    float* xpt = (float*)d_out;
    __hip_bfloat16* hs = (__hip_bfloat16*)d_ws;

    k_embed_proj_t<<<NS, G3, 0, stream>>>(tokens, emb, w_ih, b_ih, xpt);
    k_gru_scan<<<NB, 64, 0, stream>>>(xpt, w_hh, b_hh, hs);
    dim3 grid3((NB * NS) / (16 * MT), VOCAB / 256);   // x = mtile-group (fast), y = ncb
    k_logits<<<grid3, 256, 0, stream>>>(hs, w_out, b_out, d_out);
}